// Round 1
// baseline (588.610 us; speedup 1.0000x reference)
//
#include <hip/hip_runtime.h>

// ============================================================================
// TypeNet triplet embedder: 2x(LSTM + BatchNorm) + FC + L2norm, for a,p,n.
// B=512, T=128, IN=5, H=128, gates=512 (i,f,g,o). fp32 in/out.
//
// Design (round 1):
//  - Recurrence kernels: 96 WGs (16 seqs each), 4 waves, wave w owns h-cols
//    [32w,32w+32). MFMA f32_16x16x32_f16; Whh/W2 B-fragments persistent in
//    VGPRs. h exchanged via LDS (2 barriers/step). c, BN stats in fp32 regs.
//  - BN1 folded into layer2: W2s[k][g] = scale1[k]*Wih2[g][k] (fp16),
//    bias2eff[g] = bih2+bhh2 + sum_h shift1[h]*Wih2[g][h].
//  - BN2 via running sum/sumsq only + last h; finalized in head kernel.
//  - Workspace ~51.4 MB (hs1 fp16 dominates).
// ============================================================================

typedef __attribute__((ext_vector_type(8))) _Float16 half8;
typedef __attribute__((ext_vector_type(4))) float f32x4;

#define TS 128          // timesteps
#define HID 128
#define NGATE 512
#define INQ 5
#define INV_N (1.0f/65536.0f)   // 1/(B*T)

__device__ __forceinline__ float fast_sigmoid(float x) {
  return __builtin_amdgcn_rcpf(1.0f + __expf(-x));
}
__device__ __forceinline__ float fast_tanh(float x) {
  return 2.0f * __builtin_amdgcn_rcpf(1.0f + __expf(-2.0f * x)) - 1.0f;
}

// ---------------------------------------------------------------------------
// Prep: WhhT (fp16, [128 k][512 g]) for both layers; combined biases.
// ---------------------------------------------------------------------------
__global__ void prep_whhT(const float* __restrict__ Whh1,
                          const float* __restrict__ Whh2,
                          _Float16* __restrict__ whhT1,
                          _Float16* __restrict__ whhT2) {
  int i = blockIdx.x * 256 + threadIdx.x;      // 512 blocks -> 131072
  int which = i >> 16, idx = i & 65535;
  int k = idx >> 9, g = idx & 511;
  const float* src = which ? Whh2 : Whh1;
  _Float16* dst = which ? whhT2 : whhT1;
  dst[idx] = (_Float16)src[g * HID + k];
}

__global__ void prep_bias(const float* __restrict__ bih1, const float* __restrict__ bhh1,
                          const float* __restrict__ bih2, const float* __restrict__ bhh2,
                          float* __restrict__ b1c, float* __restrict__ b2c) {
  int i = blockIdx.x * 256 + threadIdx.x;      // 4 blocks -> 1024
  if (i < 512) b1c[i] = bih1[i] + bhh1[i];
  else         b2c[i - 512] = bih2[i - 512] + bhh2[i - 512];
}

// ---------------------------------------------------------------------------
// LSTM layer 1: xW1 on the fly (IN=5), writes hs1 fp16, accumulates BN1 stats.
// ---------------------------------------------------------------------------
__global__ __launch_bounds__(256, 1) void lstm1_kernel(
    const float* __restrict__ xa, const float* __restrict__ xp, const float* __restrict__ xn,
    const float* __restrict__ Wih1,      // [512][5]
    const float* __restrict__ b1c,       // [512]
    const _Float16* __restrict__ whhT,   // [128][512]
    _Float16* __restrict__ hs1,          // [1536][128][128]
    float* __restrict__ s1sum, float* __restrict__ s1sq) {
  const int wg = blockIdx.x;             // 0..95
  const int inp = wg >> 5;
  const int rloc = (wg & 31) * 16;       // row within this input
  const int gr0 = wg * 16;               // global row base
  const float* x = (inp == 0) ? xa : ((inp == 1) ? xp : xn);

  const int tid = threadIdx.x;
  const int w = tid >> 6;
  const int lane = tid & 63;
  const int l15 = lane & 15;
  const int quad = lane >> 4;

  __shared__ _Float16 h_lds[16][136];    // +8 pad
  __shared__ float x_lds[16][6];

  for (int i = tid; i < 16 * 136; i += 256) ((_Float16*)h_lds)[i] = (_Float16)0.0f;

  // Persistent B fragments: B[k][n], k = kt*32+quad*8+j, n = gcol
  half8 bfrag[4][8];
#pragma unroll
  for (int kt = 0; kt < 4; ++kt)
#pragma unroll
    for (int nt = 0; nt < 8; ++nt) {
      int gcol = (nt >> 1) * 128 + w * 32 + (nt & 1) * 16 + l15;
      int kb = kt * 32 + quad * 8;
      half8 v;
#pragma unroll
      for (int j = 0; j < 8; ++j) v[j] = whhT[(kb + j) * NGATE + gcol];
      bfrag[kt][nt] = v;
    }
  float wih[8][5], bias[8];
#pragma unroll
  for (int nt = 0; nt < 8; ++nt) {
    int gcol = (nt >> 1) * 128 + w * 32 + (nt & 1) * 16 + l15;
    bias[nt] = b1c[gcol];
#pragma unroll
    for (int d = 0; d < 5; ++d) wih[nt][d] = Wih1[gcol * INQ + d];
  }
  if (tid < 80) { int r = tid / 5, d = tid % 5; x_lds[r][d] = x[(rloc + r) * (TS * INQ) + d]; }

  float c[2][4] = {{0,0,0,0},{0,0,0,0}};
  float ssum[2] = {0, 0}, ssq[2] = {0, 0};

  for (int t = 0; t < TS; ++t) {
    __syncthreads();                     // x_lds(t), h_lds(t-1) ready
    // ---- read phase ----
    half8 afrag[4];
#pragma unroll
    for (int kt = 0; kt < 4; ++kt)
      afrag[kt] = *(const half8*)&h_lds[l15][kt * 32 + quad * 8];
    float xv[4][5];
#pragma unroll
    for (int r = 0; r < 4; ++r)
#pragma unroll
      for (int d = 0; d < 5; ++d) xv[r][d] = x_lds[quad * 4 + r][d];
    // ---- compute ----
    f32x4 acc[8];
#pragma unroll
    for (int nt = 0; nt < 8; ++nt) {
      f32x4 v;
#pragma unroll
      for (int r = 0; r < 4; ++r) {
        float s = bias[nt];
#pragma unroll
        for (int d = 0; d < 5; ++d) s += xv[r][d] * wih[nt][d];
        v[r] = s;
      }
      acc[nt] = v;
    }
#pragma unroll
    for (int kt = 0; kt < 4; ++kt)
#pragma unroll
      for (int nt = 0; nt < 8; ++nt)
        acc[nt] = __builtin_amdgcn_mfma_f32_16x16x32_f16(afrag[kt], bfrag[kt][nt], acc[nt], 0, 0, 0);
    __syncthreads();                     // all LDS reads done
    // ---- elementwise + writes ----
#pragma unroll
    for (int sub = 0; sub < 2; ++sub) {
      int col = w * 32 + sub * 16 + l15;
#pragma unroll
      for (int r = 0; r < 4; ++r) {
        float iv = fast_sigmoid(acc[0 + sub][r]);
        float fv = fast_sigmoid(acc[2 + sub][r]);
        float gv = fast_tanh(acc[4 + sub][r]);
        float ov = fast_sigmoid(acc[6 + sub][r]);
        float cc = fv * c[sub][r] + iv * gv;
        c[sub][r] = cc;
        float hv = ov * fast_tanh(cc);
        _Float16 hh = (_Float16)hv;
        float hr = (float)hh;
        ssum[sub] += hr; ssq[sub] += hr * hr;
        int row = quad * 4 + r;
        h_lds[row][col] = hh;
        hs1[((gr0 + row) * TS + t) * HID + col] = hh;
      }
    }
    if (t + 1 < TS && tid < 80) {
      int r = tid / 5, d = tid % 5;
      x_lds[r][d] = x[(rloc + r) * (TS * INQ) + (t + 1) * INQ + d];
    }
  }
  // ---- BN1 stats: reduce rows (lanes sharing lane&15), one atomic per col ----
#pragma unroll
  for (int sub = 0; sub < 2; ++sub) {
    float s = ssum[sub], q = ssq[sub];
    s += __shfl_xor(s, 16); s += __shfl_xor(s, 32);
    q += __shfl_xor(q, 16); q += __shfl_xor(q, 32);
    if (quad == 0) {
      int col = w * 32 + sub * 16 + l15;
      atomicAdd(&s1sum[inp * HID + col], s);
      atomicAdd(&s1sq[inp * HID + col], q);
    }
  }
}

// ---------------------------------------------------------------------------
// BN1 finalize, scaled W2, effective bias2
// ---------------------------------------------------------------------------
__global__ void finalize1_kernel(const float* __restrict__ s1sum, const float* __restrict__ s1sq,
                                 const float* __restrict__ g1, const float* __restrict__ b1,
                                 float* __restrict__ scale1, float* __restrict__ shift1) {
  int i = blockIdx.x * 128 + threadIdx.x;   // 3 blocks x 128
  int h = i & 127;
  float m = s1sum[i] * INV_N;
  float v = s1sq[i] * INV_N - m * m;
  float s = g1[h] * rsqrtf(v + 1e-5f);
  scale1[i] = s;
  shift1[i] = b1[h] - m * s;
}

__global__ void w2s_kernel(const float* __restrict__ scale1, const float* __restrict__ Wih2,
                           _Float16* __restrict__ w2s) {
  int i = blockIdx.x * 256 + threadIdx.x;   // 768 blocks -> 196608 = [3][128 k][512 g]
  int inp = i >> 16, rem = i & 65535, k = rem >> 9, g = rem & 511;
  w2s[i] = (_Float16)(scale1[inp * HID + k] * Wih2[g * HID + k]);
}

__global__ void bias2_kernel(const float* __restrict__ shift1, const float* __restrict__ Wih2,
                             const float* __restrict__ b2c, float* __restrict__ bias2eff) {
  int i = blockIdx.x * 512 + threadIdx.x;   // 3 blocks x 512
  int inp = i >> 9, g = i & 511;
  float acc = b2c[g];
  for (int h = 0; h < HID; ++h) acc += shift1[inp * HID + h] * Wih2[g * HID + h];
  bias2eff[i] = acc;
}

// ---------------------------------------------------------------------------
// LSTM layer 2: fused input GEMM (bn1(hs1) @ Wih2^T via folded W2s) +
// recurrence. Accumulates BN2 stats; stores only final h.
// ---------------------------------------------------------------------------
__global__ __launch_bounds__(256, 1) void lstm2_kernel(
    const _Float16* __restrict__ hs1,    // [1536][128][128]
    const _Float16* __restrict__ whhT2,  // [128][512]
    const _Float16* __restrict__ w2s,    // [3][128][512]
    const float* __restrict__ bias2eff,  // [3][512]
    _Float16* __restrict__ h_last,       // [1536][128]
    float* __restrict__ s2sum, float* __restrict__ s2sq) {
  const int wg = blockIdx.x;
  const int inp = wg >> 5;
  const int gr0 = wg * 16;

  const int tid = threadIdx.x;
  const int w = tid >> 6;
  const int lane = tid & 63;
  const int l15 = lane & 15;
  const int quad = lane >> 4;

  __shared__ _Float16 h_lds[16][136];
  for (int i = tid; i < 16 * 136; i += 256) ((_Float16*)h_lds)[i] = (_Float16)0.0f;

  const _Float16* w2sI = w2s + inp * (HID * NGATE);
  half8 bfragH[4][8], bfragX[4][8];
#pragma unroll
  for (int kt = 0; kt < 4; ++kt)
#pragma unroll
    for (int nt = 0; nt < 8; ++nt) {
      int gcol = (nt >> 1) * 128 + w * 32 + (nt & 1) * 16 + l15;
      int kb = kt * 32 + quad * 8;
      half8 vh, vx;
#pragma unroll
      for (int j = 0; j < 8; ++j) {
        vh[j] = whhT2[(kb + j) * NGATE + gcol];
        vx[j] = w2sI[(kb + j) * NGATE + gcol];
      }
      bfragH[kt][nt] = vh;
      bfragX[kt][nt] = vx;
    }
  float bias[8];
#pragma unroll
  for (int nt = 0; nt < 8; ++nt) {
    int gcol = (nt >> 1) * 128 + w * 32 + (nt & 1) * 16 + l15;
    bias[nt] = bias2eff[inp * NGATE + gcol];
  }

  float c[2][4] = {{0,0,0,0},{0,0,0,0}};
  float ssum[2] = {0, 0}, ssq[2] = {0, 0};

  for (int t = 0; t < TS; ++t) {
    // layer-1 activations for this step (global, no LDS dependency)
    half8 a2[4];
#pragma unroll
    for (int kt = 0; kt < 4; ++kt)
      a2[kt] = *(const half8*)&hs1[((gr0 + l15) * TS + t) * HID + kt * 32 + quad * 8];
    __syncthreads();                     // h_lds(t-1) ready
    half8 ah[4];
#pragma unroll
    for (int kt = 0; kt < 4; ++kt)
      ah[kt] = *(const half8*)&h_lds[l15][kt * 32 + quad * 8];
    f32x4 acc[8];
#pragma unroll
    for (int nt = 0; nt < 8; ++nt) {
      f32x4 v; v[0] = bias[nt]; v[1] = bias[nt]; v[2] = bias[nt]; v[3] = bias[nt];
      acc[nt] = v;
    }
#pragma unroll
    for (int kt = 0; kt < 4; ++kt)
#pragma unroll
      for (int nt = 0; nt < 8; ++nt)
        acc[nt] = __builtin_amdgcn_mfma_f32_16x16x32_f16(a2[kt], bfragX[kt][nt], acc[nt], 0, 0, 0);
#pragma unroll
    for (int kt = 0; kt < 4; ++kt)
#pragma unroll
      for (int nt = 0; nt < 8; ++nt)
        acc[nt] = __builtin_amdgcn_mfma_f32_16x16x32_f16(ah[kt], bfragH[kt][nt], acc[nt], 0, 0, 0);
    __syncthreads();                     // LDS reads done
#pragma unroll
    for (int sub = 0; sub < 2; ++sub) {
      int col = w * 32 + sub * 16 + l15;
#pragma unroll
      for (int r = 0; r < 4; ++r) {
        float iv = fast_sigmoid(acc[0 + sub][r]);
        float fv = fast_sigmoid(acc[2 + sub][r]);
        float gv = fast_tanh(acc[4 + sub][r]);
        float ov = fast_sigmoid(acc[6 + sub][r]);
        float cc = fv * c[sub][r] + iv * gv;
        c[sub][r] = cc;
        float hv = ov * fast_tanh(cc);
        _Float16 hh = (_Float16)hv;
        float hr = (float)hh;
        ssum[sub] += hr; ssq[sub] += hr * hr;
        int row = quad * 4 + r;
        h_lds[row][col] = hh;
        if (t == TS - 1) h_last[(gr0 + row) * HID + col] = hh;
      }
    }
  }
#pragma unroll
  for (int sub = 0; sub < 2; ++sub) {
    float s = ssum[sub], q = ssq[sub];
    s += __shfl_xor(s, 16); s += __shfl_xor(s, 32);
    q += __shfl_xor(q, 16); q += __shfl_xor(q, 32);
    if (quad == 0) {
      int col = w * 32 + sub * 16 + l15;
      atomicAdd(&s2sum[inp * HID + col], s);
      atomicAdd(&s2sq[inp * HID + col], q);
    }
  }
}

// ---------------------------------------------------------------------------
// Head: BN2 finalize + FC + L2 normalize. 96 WGs x 16 rows.
// ---------------------------------------------------------------------------
__global__ __launch_bounds__(256, 1) void head_kernel(
    const _Float16* __restrict__ h_last,
    const float* __restrict__ s2sum, const float* __restrict__ s2sq,
    const float* __restrict__ g2, const float* __restrict__ b2,
    const float* __restrict__ fcW, const float* __restrict__ fcb,
    float* __restrict__ out) {
  const int wg = blockIdx.x;
  const int inp = wg >> 5;
  const int gr0 = wg * 16;
  const int tid = threadIdx.x;

  __shared__ float fcwT[128][132];       // fcwT[h][j] = fcW[j][h]
  __shared__ float bnh[16][132];
  __shared__ float s2[128], sh2[128];
  __shared__ float part[16][16];
  __shared__ float inv[16];

  if (tid < 128) {
    float m = s2sum[inp * HID + tid] * INV_N;
    float v = s2sq[inp * HID + tid] * INV_N - m * m;
    float s = g2[tid] * rsqrtf(v + 1e-5f);
    s2[tid] = s; sh2[tid] = b2[tid] - m * s;
  }
  for (int i = tid; i < 16384; i += 256) {
    int j = i >> 7, h = i & 127;
    fcwT[h][j] = fcW[i];
  }
  __syncthreads();
  {
    int row = tid >> 4, c0 = (tid & 15) * 8;
#pragma unroll
    for (int k = 0; k < 8; ++k) {
      int h = c0 + k;
      bnh[row][h] = (float)h_last[(gr0 + row) * HID + h] * s2[h] + sh2[h];
    }
  }
  __syncthreads();
  const int row = tid >> 4, jl = tid & 15;
  float emb[8];
  float sq = 0.0f;
#pragma unroll
  for (int jj = 0; jj < 8; ++jj) {
    int j = jl + jj * 16;
    float acc = fcb[j];
    for (int h = 0; h < HID; ++h) acc += bnh[row][h] * fcwT[h][j];
    emb[jj] = acc; sq += acc * acc;
  }
  part[row][jl] = sq;
  __syncthreads();
  if (tid < 16) {
    float s = 0.0f;
    for (int k = 0; k < 16; ++k) s += part[tid][k];
    float nrm = sqrtf(s);
    inv[tid] = 1.0f / fmaxf(nrm, 1e-12f);
  }
  __syncthreads();
#pragma unroll
  for (int jj = 0; jj < 8; ++jj)
    out[(gr0 + row) * HID + jl + jj * 16] = emb[jj] * inv[row];
}

// ---------------------------------------------------------------------------
extern "C" void kernel_launch(void* const* d_in, const int* in_sizes, int n_in,
                              void* d_out, int out_size, void* d_ws, size_t ws_size,
                              hipStream_t stream) {
  const float* a    = (const float*)d_in[0];
  const float* p    = (const float*)d_in[1];
  const float* nn   = (const float*)d_in[2];
  const float* Wih1 = (const float*)d_in[3];
  const float* Whh1 = (const float*)d_in[4];
  const float* bih1 = (const float*)d_in[5];
  const float* bhh1 = (const float*)d_in[6];
  const float* g1   = (const float*)d_in[7];
  const float* b1   = (const float*)d_in[8];
  const float* Wih2 = (const float*)d_in[9];
  const float* Whh2 = (const float*)d_in[10];
  const float* bih2 = (const float*)d_in[11];
  const float* bhh2 = (const float*)d_in[12];
  const float* g2   = (const float*)d_in[13];
  const float* b2   = (const float*)d_in[14];
  const float* fcW  = (const float*)d_in[15];
  const float* fcb  = (const float*)d_in[16];

  char* ws = (char*)d_ws;
  float* s1sum = (float*)(ws + 0);           // 384
  float* s1sq  = s1sum + 384;
  float* s2sum = s1sum + 768;
  float* s2sq  = s1sum + 1152;               // stats end @6144B
  float* b1c   = (float*)(ws + 6144);        // 512
  float* b2c   = b1c + 512;                  // ends @10240B
  float* scale1 = (float*)(ws + 10240);      // 384
  float* shift1 = scale1 + 384;              // ends @13312B
  float* bias2eff = (float*)(ws + 13312);    // 1536 -> ends @19456B
  _Float16* whhT1 = (_Float16*)(ws + 19456);   // 65536 -> @150528
  _Float16* whhT2 = (_Float16*)(ws + 150528);  // 65536 -> @281600
  _Float16* w2s   = (_Float16*)(ws + 281600);  // 196608 -> @674816
  _Float16* hlast = (_Float16*)(ws + 674816);  // 196608 -> @1068032
  _Float16* hs1   = (_Float16*)(ws + 1068032); // 25165824 -> ~51.4MB total

  hipMemsetAsync(ws, 0, 6144, stream);  // zero BN stats accumulators

  prep_whhT<<<512, 256, 0, stream>>>(Whh1, Whh2, whhT1, whhT2);
  prep_bias<<<4, 256, 0, stream>>>(bih1, bhh1, bih2, bhh2, b1c, b2c);
  lstm1_kernel<<<96, 256, 0, stream>>>(a, p, nn, Wih1, b1c, whhT1, hs1, s1sum, s1sq);
  finalize1_kernel<<<3, 128, 0, stream>>>(s1sum, s1sq, g1, b1, scale1, shift1);
  w2s_kernel<<<768, 256, 0, stream>>>(scale1, Wih2, w2s);
  bias2_kernel<<<3, 512, 0, stream>>>(shift1, Wih2, b2c, bias2eff);
  lstm2_kernel<<<96, 256, 0, stream>>>(hs1, whhT2, w2s, bias2eff, hlast, s2sum, s2sq);
  head_kernel<<<96, 256, 0, stream>>>(hlast, s2sum, s2sq, g2, b2, fcW, fcb, (float*)d_out);
}

// Round 2
// 434.236 us; speedup vs baseline: 1.3555x; 1.3555x over previous
//
#include <hip/hip_runtime.h>

// ============================================================================
// TypeNet triplet embedder: 2x(LSTM + BatchNorm) + FC + L2norm, for a,p,n.
// Round 2: latency-bound fix.
//  - 512-thread WGs (8 waves, 2 waves/SIMD). Wave w owns h-cols [16w,16w+16):
//    4 gate accs (i,f,g,o), B-frags 64 VGPR/matrix, 4-elem elementwise tail.
//  - ONE barrier/step via double-buffered h LDS (read buf[t&1], write buf[~]).
//  - lstm2: hs1 re-laid out [wg][t][16][128] -> coalesced A-frag loads,
//    software-pipelined 1 step ahead (full-step hiding window).
//  - lstm1: x staged to LDS fp16 once; xW via padded-K MFMA (IN=5 -> K=32),
//    replaces 160 VALU FMAs/lane/step with 4 MFMAs.
// ============================================================================

typedef __attribute__((ext_vector_type(8))) _Float16 half8;
typedef __attribute__((ext_vector_type(4))) float f32x4;

#define TS 128
#define HID 128
#define NGATE 512
#define INQ 5
#define INV_N (1.0f/65536.0f)   // 1/(B*T)

__device__ __forceinline__ float fast_sigmoid(float x) {
  return __builtin_amdgcn_rcpf(1.0f + __expf(-x));
}
__device__ __forceinline__ float fast_tanh(float x) {
  return 2.0f * __builtin_amdgcn_rcpf(1.0f + __expf(-2.0f * x)) - 1.0f;
}

// ---------------------------------------------------------------------------
__global__ void prep_whhT(const float* __restrict__ Whh1,
                          const float* __restrict__ Whh2,
                          _Float16* __restrict__ whhT1,
                          _Float16* __restrict__ whhT2) {
  int i = blockIdx.x * 256 + threadIdx.x;      // 512 blocks -> 131072
  int which = i >> 16, idx = i & 65535;
  int k = idx >> 9, g = idx & 511;
  const float* src = which ? Whh2 : Whh1;
  _Float16* dst = which ? whhT2 : whhT1;
  dst[idx] = (_Float16)src[g * HID + k];
}

__global__ void prep_bias(const float* __restrict__ bih1, const float* __restrict__ bhh1,
                          const float* __restrict__ bih2, const float* __restrict__ bhh2,
                          float* __restrict__ b1c, float* __restrict__ b2c) {
  int i = blockIdx.x * 256 + threadIdx.x;      // 4 blocks -> 1024
  if (i < 512) b1c[i] = bih1[i] + bhh1[i];
  else         b2c[i - 512] = bih2[i - 512] + bhh2[i - 512];
}

// ---------------------------------------------------------------------------
// LSTM layer 1. hs1 layout: [96 wg][128 t][16 r][128 c] fp16.
// ---------------------------------------------------------------------------
__global__ __launch_bounds__(512, 2) void lstm1_kernel(
    const float* __restrict__ xa, const float* __restrict__ xp, const float* __restrict__ xn,
    const float* __restrict__ Wih1,      // [512][5]
    const float* __restrict__ b1c,       // [512]
    const _Float16* __restrict__ whhT,   // [128 k][512 g]
    _Float16* __restrict__ hs1,
    float* __restrict__ s1sum, float* __restrict__ s1sq) {
  const int wg = blockIdx.x;             // 0..95
  const int inp = wg >> 5;
  const int rloc = (wg & 31) * 16;
  const float* x = (inp == 0) ? xa : ((inp == 1) ? xp : xn);

  const int tid = threadIdx.x;
  const int w = tid >> 6;                // 0..7
  const int lane = tid & 63;
  const int l15 = lane & 15;
  const int quad = lane >> 4;
  const int col = w * 16 + l15;          // h column owned by this lane
  const int kb = quad * 8;

  __shared__ _Float16 hbuf[2][16][136];  // double-buffered h, +8 pad
  __shared__ _Float16 xt_lds[TS][16][8]; // x fp16, K-padded to 8 (d>=5 zero)

  for (int i = tid; i < 16 * 136; i += 512) ((_Float16*)hbuf[0])[i] = (_Float16)0.0f;
  for (int i = tid; i < TS * 16 * 8; i += 512) ((_Float16*)xt_lds)[i] = (_Float16)0.0f;
  __syncthreads();                       // zero-fill complete before data fill
  for (int i = tid; i < 16 * TS * INQ; i += 512) {
    int r = i / 640, rem = i - r * 640;
    int t = rem / 5, d = rem - t * 5;
    xt_lds[t][r][d] = (_Float16)x[(rloc + r) * 640 + rem];
  }

  // Persistent B fragments. B[k][n]: n = gate col (l15-derived), k = kt*32+quad*8+j
  half8 bh[4][4];                        // [kt][gate]
#pragma unroll
  for (int kt = 0; kt < 4; ++kt)
#pragma unroll
    for (int gt = 0; gt < 4; ++gt) {
      int gcol = gt * 128 + col;
      half8 v;
#pragma unroll
      for (int j = 0; j < 8; ++j) v[j] = whhT[(kt * 32 + kb + j) * NGATE + gcol];
      bh[kt][gt] = v;
    }
  half8 bx[4];                           // Wih1 as K=32-padded B frag (only quad0, j<5 nonzero)
#pragma unroll
  for (int gt = 0; gt < 4; ++gt) {
    half8 v = {0, 0, 0, 0, 0, 0, 0, 0};
    if (quad == 0) {
#pragma unroll
      for (int j = 0; j < 5; ++j) v[j] = (_Float16)Wih1[(gt * 128 + col) * INQ + j];
    }
    bx[gt] = v;
  }
  float bias[4];
#pragma unroll
  for (int gt = 0; gt < 4; ++gt) bias[gt] = b1c[gt * 128 + col];

  float c[4] = {0, 0, 0, 0};
  float ssum = 0.0f, ssq = 0.0f;
  _Float16* hs1w = hs1 + (size_t)wg * TS * 16 * HID;

  for (int t = 0; t < TS; ++t) {
    __syncthreads();                     // hbuf[t&1] (and x at t=0) ready
    half8 ah[4];
#pragma unroll
    for (int kt = 0; kt < 4; ++kt)
      ah[kt] = *(const half8*)&hbuf[t & 1][l15][kt * 32 + kb];
    half8 ax = {0, 0, 0, 0, 0, 0, 0, 0};
    if (quad == 0) ax = *(const half8*)&xt_lds[t][l15][0];
    f32x4 acc[4];
#pragma unroll
    for (int gt = 0; gt < 4; ++gt) {
      f32x4 v; v[0] = bias[gt]; v[1] = bias[gt]; v[2] = bias[gt]; v[3] = bias[gt];
      acc[gt] = v;
    }
#pragma unroll
    for (int gt = 0; gt < 4; ++gt)
      acc[gt] = __builtin_amdgcn_mfma_f32_16x16x32_f16(ax, bx[gt], acc[gt], 0, 0, 0);
#pragma unroll
    for (int kt = 0; kt < 4; ++kt)
#pragma unroll
      for (int gt = 0; gt < 4; ++gt)
        acc[gt] = __builtin_amdgcn_mfma_f32_16x16x32_f16(ah[kt], bh[kt][gt], acc[gt], 0, 0, 0);
#pragma unroll
    for (int r = 0; r < 4; ++r) {
      float iv = fast_sigmoid(acc[0][r]);
      float fv = fast_sigmoid(acc[1][r]);
      float gv = fast_tanh(acc[2][r]);
      float ov = fast_sigmoid(acc[3][r]);
      float cc = fv * c[r] + iv * gv;
      c[r] = cc;
      float hv = ov * fast_tanh(cc);
      _Float16 hh = (_Float16)hv;
      float hr = (float)hh;
      ssum += hr; ssq += hr * hr;
      int row = quad * 4 + r;
      hbuf[(t + 1) & 1][row][col] = hh;
      hs1w[((size_t)t * 16 + row) * HID + col] = hh;
    }
  }
  float s = ssum, q = ssq;
  s += __shfl_xor(s, 16); s += __shfl_xor(s, 32);
  q += __shfl_xor(q, 16); q += __shfl_xor(q, 32);
  if (quad == 0) {
    atomicAdd(&s1sum[inp * HID + col], s);
    atomicAdd(&s1sq[inp * HID + col], q);
  }
}

// ---------------------------------------------------------------------------
__global__ void finalize1_kernel(const float* __restrict__ s1sum, const float* __restrict__ s1sq,
                                 const float* __restrict__ g1, const float* __restrict__ b1,
                                 float* __restrict__ scale1, float* __restrict__ shift1) {
  int i = blockIdx.x * 128 + threadIdx.x;   // 3 blocks x 128
  int h = i & 127;
  float m = s1sum[i] * INV_N;
  float v = s1sq[i] * INV_N - m * m;
  float s = g1[h] * rsqrtf(v + 1e-5f);
  scale1[i] = s;
  shift1[i] = b1[h] - m * s;
}

__global__ void w2s_kernel(const float* __restrict__ scale1, const float* __restrict__ Wih2,
                           _Float16* __restrict__ w2s) {
  int i = blockIdx.x * 256 + threadIdx.x;   // 768 blocks -> [3][128 k][512 g]
  int inp = i >> 16, rem = i & 65535, k = rem >> 9, g = rem & 511;
  w2s[i] = (_Float16)(scale1[inp * HID + k] * Wih2[g * HID + k]);
}

__global__ void bias2_kernel(const float* __restrict__ shift1, const float* __restrict__ Wih2,
                             const float* __restrict__ b2c, float* __restrict__ bias2eff) {
  int i = blockIdx.x * 512 + threadIdx.x;   // 3 blocks x 512
  int inp = i >> 9, g = i & 511;
  float acc = b2c[g];
  for (int h = 0; h < HID; ++h) acc += shift1[inp * HID + h] * Wih2[g * HID + h];
  bias2eff[i] = acc;
}

// ---------------------------------------------------------------------------
// LSTM layer 2: fused (folded-BN1) input GEMM + recurrence, prefetched hs1.
// ---------------------------------------------------------------------------
__global__ __launch_bounds__(512, 2) void lstm2_kernel(
    const _Float16* __restrict__ hs1,    // [96][128][16][128]
    const _Float16* __restrict__ whhT2,  // [128 k][512 g]
    const _Float16* __restrict__ w2s,    // [3][128 k][512 g]
    const float* __restrict__ bias2eff,  // [3][512]
    _Float16* __restrict__ h_last,       // [1536][128]
    float* __restrict__ s2sum, float* __restrict__ s2sq) {
  const int wg = blockIdx.x;
  const int inp = wg >> 5;
  const int gr0 = wg * 16;

  const int tid = threadIdx.x;
  const int w = tid >> 6;
  const int lane = tid & 63;
  const int l15 = lane & 15;
  const int quad = lane >> 4;
  const int col = w * 16 + l15;
  const int kb = quad * 8;

  __shared__ _Float16 hbuf[2][16][136];
  for (int i = tid; i < 16 * 136; i += 512) ((_Float16*)hbuf[0])[i] = (_Float16)0.0f;

  const _Float16* w2sI = w2s + (size_t)inp * HID * NGATE;
  half8 bh[4][4], bxw[4][4];
#pragma unroll
  for (int kt = 0; kt < 4; ++kt)
#pragma unroll
    for (int gt = 0; gt < 4; ++gt) {
      int gcol = gt * 128 + col;
      half8 vh, vx;
#pragma unroll
      for (int j = 0; j < 8; ++j) {
        vh[j] = whhT2[(kt * 32 + kb + j) * NGATE + gcol];
        vx[j] = w2sI[(kt * 32 + kb + j) * NGATE + gcol];
      }
      bh[kt][gt] = vh;
      bxw[kt][gt] = vx;
    }
  float bias[4];
#pragma unroll
  for (int gt = 0; gt < 4; ++gt) bias[gt] = bias2eff[inp * NGATE + gt * 128 + col];

  const _Float16* hg = hs1 + (size_t)wg * TS * 16 * HID;
  half8 a2A[4], a2B[4];
#pragma unroll
  for (int kt = 0; kt < 4; ++kt)
    a2A[kt] = *(const half8*)&hg[(size_t)l15 * HID + kt * 32 + kb];

  float c[4] = {0, 0, 0, 0};
  float ssum = 0.0f, ssq = 0.0f;

  auto step = [&](int t, half8 (&cur)[4], half8 (&nxt)[4]) {
    __syncthreads();                     // hbuf[t&1] writes from t-1 complete
    half8 ah[4];
#pragma unroll
    for (int kt = 0; kt < 4; ++kt)
      ah[kt] = *(const half8*)&hbuf[t & 1][l15][kt * 32 + kb];
    if (t + 1 < TS) {                    // prefetch next step's layer-1 tile
#pragma unroll
      for (int kt = 0; kt < 4; ++kt)
        nxt[kt] = *(const half8*)&hg[((size_t)(t + 1) * 16 + l15) * HID + kt * 32 + kb];
    }
    f32x4 acc[4];
#pragma unroll
    for (int gt = 0; gt < 4; ++gt) {
      f32x4 v; v[0] = bias[gt]; v[1] = bias[gt]; v[2] = bias[gt]; v[3] = bias[gt];
      acc[gt] = v;
    }
#pragma unroll
    for (int kt = 0; kt < 4; ++kt)
#pragma unroll
      for (int gt = 0; gt < 4; ++gt)
        acc[gt] = __builtin_amdgcn_mfma_f32_16x16x32_f16(cur[kt], bxw[kt][gt], acc[gt], 0, 0, 0);
#pragma unroll
    for (int kt = 0; kt < 4; ++kt)
#pragma unroll
      for (int gt = 0; gt < 4; ++gt)
        acc[gt] = __builtin_amdgcn_mfma_f32_16x16x32_f16(ah[kt], bh[kt][gt], acc[gt], 0, 0, 0);
#pragma unroll
    for (int r = 0; r < 4; ++r) {
      float iv = fast_sigmoid(acc[0][r]);
      float fv = fast_sigmoid(acc[1][r]);
      float gv = fast_tanh(acc[2][r]);
      float ov = fast_sigmoid(acc[3][r]);
      float cc = fv * c[r] + iv * gv;
      c[r] = cc;
      float hv = ov * fast_tanh(cc);
      _Float16 hh = (_Float16)hv;
      float hr = (float)hh;
      ssum += hr; ssq += hr * hr;
      int row = quad * 4 + r;
      hbuf[(t + 1) & 1][row][col] = hh;
      if (t == TS - 1) h_last[(gr0 + row) * HID + col] = hh;
    }
  };

  for (int t = 0; t < TS; t += 2) {
    step(t, a2A, a2B);
    step(t + 1, a2B, a2A);
  }

  float s = ssum, q = ssq;
  s += __shfl_xor(s, 16); s += __shfl_xor(s, 32);
  q += __shfl_xor(q, 16); q += __shfl_xor(q, 32);
  if (quad == 0) {
    atomicAdd(&s2sum[inp * HID + col], s);
    atomicAdd(&s2sq[inp * HID + col], q);
  }
}

// ---------------------------------------------------------------------------
// Head: BN2 finalize + FC + L2 normalize. 96 WGs x 16 rows.
// ---------------------------------------------------------------------------
__global__ __launch_bounds__(256, 1) void head_kernel(
    const _Float16* __restrict__ h_last,
    const float* __restrict__ s2sum, const float* __restrict__ s2sq,
    const float* __restrict__ g2, const float* __restrict__ b2,
    const float* __restrict__ fcW, const float* __restrict__ fcb,
    float* __restrict__ out) {
  const int wg = blockIdx.x;
  const int inp = wg >> 5;
  const int gr0 = wg * 16;
  const int tid = threadIdx.x;

  __shared__ float fcwT[128][132];       // fcwT[h][j] = fcW[j][h]
  __shared__ float bnh[16][132];
  __shared__ float s2[128], sh2[128];
  __shared__ float part[16][16];
  __shared__ float inv[16];

  if (tid < 128) {
    float m = s2sum[inp * HID + tid] * INV_N;
    float v = s2sq[inp * HID + tid] * INV_N - m * m;
    float s = g2[tid] * rsqrtf(v + 1e-5f);
    s2[tid] = s; sh2[tid] = b2[tid] - m * s;
  }
  for (int i = tid; i < 16384; i += 256) {
    int j = i >> 7, h = i & 127;
    fcwT[h][j] = fcW[i];
  }
  __syncthreads();
  {
    int row = tid >> 4, c0 = (tid & 15) * 8;
#pragma unroll
    for (int k = 0; k < 8; ++k) {
      int h = c0 + k;
      bnh[row][h] = (float)h_last[(gr0 + row) * HID + h] * s2[h] + sh2[h];
    }
  }
  __syncthreads();
  const int row = tid >> 4, jl = tid & 15;
  float emb[8];
  float sq = 0.0f;
#pragma unroll
  for (int jj = 0; jj < 8; ++jj) {
    int j = jl + jj * 16;
    float acc = fcb[j];
    for (int h = 0; h < HID; ++h) acc += bnh[row][h] * fcwT[h][j];
    emb[jj] = acc; sq += acc * acc;
  }
  part[row][jl] = sq;
  __syncthreads();
  if (tid < 16) {
    float s = 0.0f;
    for (int k = 0; k < 16; ++k) s += part[tid][k];
    float nrm = sqrtf(s);
    inv[tid] = 1.0f / fmaxf(nrm, 1e-12f);
  }
  __syncthreads();
#pragma unroll
  for (int jj = 0; jj < 8; ++jj)
    out[(gr0 + row) * HID + jl + jj * 16] = emb[jj] * inv[row];
}

// ---------------------------------------------------------------------------
extern "C" void kernel_launch(void* const* d_in, const int* in_sizes, int n_in,
                              void* d_out, int out_size, void* d_ws, size_t ws_size,
                              hipStream_t stream) {
  const float* a    = (const float*)d_in[0];
  const float* p    = (const float*)d_in[1];
  const float* nn   = (const float*)d_in[2];
  const float* Wih1 = (const float*)d_in[3];
  const float* Whh1 = (const float*)d_in[4];
  const float* bih1 = (const float*)d_in[5];
  const float* bhh1 = (const float*)d_in[6];
  const float* g1   = (const float*)d_in[7];
  const float* b1   = (const float*)d_in[8];
  const float* Wih2 = (const float*)d_in[9];
  const float* Whh2 = (const float*)d_in[10];
  const float* bih2 = (const float*)d_in[11];
  const float* bhh2 = (const float*)d_in[12];
  const float* g2   = (const float*)d_in[13];
  const float* b2   = (const float*)d_in[14];
  const float* fcW  = (const float*)d_in[15];
  const float* fcb  = (const float*)d_in[16];

  char* ws = (char*)d_ws;
  float* s1sum = (float*)(ws + 0);           // 384
  float* s1sq  = s1sum + 384;
  float* s2sum = s1sum + 768;
  float* s2sq  = s1sum + 1152;               // stats end @6144B
  float* b1c   = (float*)(ws + 6144);        // 512
  float* b2c   = b1c + 512;                  // ends @10240B
  float* scale1 = (float*)(ws + 10240);      // 384
  float* shift1 = scale1 + 384;              // ends @13312B
  float* bias2eff = (float*)(ws + 13312);    // 1536 -> ends @19456B
  _Float16* whhT1 = (_Float16*)(ws + 19456);   // 65536 -> @150528
  _Float16* whhT2 = (_Float16*)(ws + 150528);  // 65536 -> @281600
  _Float16* w2s   = (_Float16*)(ws + 281600);  // 196608 -> @674816
  _Float16* hlast = (_Float16*)(ws + 674816);  // 196608 -> @1068032
  _Float16* hs1   = (_Float16*)(ws + 1068032); // 25165824 -> ~51.4MB total

  hipMemsetAsync(ws, 0, 6144, stream);  // zero BN stats accumulators

  prep_whhT<<<512, 256, 0, stream>>>(Whh1, Whh2, whhT1, whhT2);
  prep_bias<<<4, 256, 0, stream>>>(bih1, bhh1, bih2, bhh2, b1c, b2c);
  lstm1_kernel<<<96, 512, 0, stream>>>(a, p, nn, Wih1, b1c, whhT1, hs1, s1sum, s1sq);
  finalize1_kernel<<<3, 128, 0, stream>>>(s1sum, s1sq, g1, b1, scale1, shift1);
  w2s_kernel<<<768, 256, 0, stream>>>(scale1, Wih2, w2s);
  bias2_kernel<<<3, 512, 0, stream>>>(shift1, Wih2, b2c, bias2eff);
  lstm2_kernel<<<96, 512, 0, stream>>>(hs1, whhT2, w2s, bias2eff, hlast, s2sum, s2sq);
  head_kernel<<<96, 256, 0, stream>>>(hlast, s2sum, s2sq, g2, b2, fcW, fcb, (float*)d_out);
}

// Round 3
// 392.615 us; speedup vs baseline: 1.4992x; 1.1060x over previous
//
#include <hip/hip_runtime.h>

// ============================================================================
// TypeNet triplet embedder: 2x(LSTM + BatchNorm) + FC + L2norm, for a,p,n.
// Round 3: kill the per-step vmcnt(0) barrier drain.
//  - Step loops use a custom barrier: s_waitcnt lgkmcnt(0) + s_barrier (asm).
//    Cross-wave h goes through LDS only => lgkm drain suffices; global
//    prefetch loads / h stores stay in flight across barriers.
//  - lstm2: 2-step-ahead register prefetch of hs1 tiles.
//  - x-part MFMAs before the barrier; bias as MFMA C operand (no acc movs).
//  - Elementwise: 8 trans/elem (fused i*g and o*tanh(c)); clamped exp args.
// ============================================================================

typedef __attribute__((ext_vector_type(8))) _Float16 half8;
typedef __attribute__((ext_vector_type(4))) float f32x4;

#define TS 128
#define HID 128
#define NGATE 512
#define INQ 5
#define INV_N (1.0f/65536.0f)   // 1/(B*T)

// Barrier WITHOUT the implicit vmcnt(0) drain of __syncthreads().
// Safe here: all cross-wave data in the step loop moves through LDS.
#define BAR() asm volatile("s_waitcnt lgkmcnt(0)\n\ts_barrier" ::: "memory")

__device__ __forceinline__ float rcpf(float x) { return __builtin_amdgcn_rcpf(x); }
__device__ __forceinline__ float clamp20(float x) { return fminf(fmaxf(x, -20.0f), 20.0f); }

// ---------------------------------------------------------------------------
__global__ void prep_whhT(const float* __restrict__ Whh1,
                          const float* __restrict__ Whh2,
                          _Float16* __restrict__ whhT1,
                          _Float16* __restrict__ whhT2) {
  int i = blockIdx.x * 256 + threadIdx.x;      // 512 blocks -> 131072
  int which = i >> 16, idx = i & 65535;
  int k = idx >> 9, g = idx & 511;
  const float* src = which ? Whh2 : Whh1;
  _Float16* dst = which ? whhT2 : whhT1;
  dst[idx] = (_Float16)src[g * HID + k];
}

__global__ void prep_bias(const float* __restrict__ bih1, const float* __restrict__ bhh1,
                          const float* __restrict__ bih2, const float* __restrict__ bhh2,
                          float* __restrict__ b1c, float* __restrict__ b2c) {
  int i = blockIdx.x * 256 + threadIdx.x;      // 4 blocks -> 1024
  if (i < 512) b1c[i] = bih1[i] + bhh1[i];
  else         b2c[i - 512] = bih2[i - 512] + bhh2[i - 512];
}

// ---------------------------------------------------------------------------
// Fused LSTM gate elementwise: returns h (fp16), updates c. 8 trans/elem.
__device__ __forceinline__ _Float16 lstm_cell(float zi, float zf, float zg, float zo,
                                              float& c) {
  zg = clamp20(zg);
  float ei = __expf(-zi);
  float eg = __expf(-2.0f * zg);
  float ef = __expf(-zf);
  float fv = rcpf(1.0f + ef);
  float ig = (1.0f - eg) * rcpf((1.0f + ei) * (1.0f + eg));  // sigmoid(zi)*tanh(zg)
  float cc = fv * c + ig;
  c = cc;
  float ccl = clamp20(cc);
  float eo = __expf(-zo);
  float ec = __expf(-2.0f * ccl);
  float hv = (1.0f - ec) * rcpf((1.0f + eo) * (1.0f + ec));  // sigmoid(zo)*tanh(cc)
  return (_Float16)hv;
}

// ---------------------------------------------------------------------------
// LSTM layer 1. hs1 layout: [96 wg][128 t][16 r][128 c] fp16.
// ---------------------------------------------------------------------------
__global__ __launch_bounds__(512, 2) void lstm1_kernel(
    const float* __restrict__ xa, const float* __restrict__ xp, const float* __restrict__ xn,
    const float* __restrict__ Wih1,      // [512][5]
    const float* __restrict__ b1c,       // [512]
    const _Float16* __restrict__ whhT,   // [128 k][512 g]
    _Float16* __restrict__ hs1,
    float* __restrict__ s1sum, float* __restrict__ s1sq) {
  const int wg = blockIdx.x;             // 0..95
  const int inp = wg >> 5;
  const int rloc = (wg & 31) * 16;
  const float* x = (inp == 0) ? xa : ((inp == 1) ? xp : xn);

  const int tid = threadIdx.x;
  const int w = tid >> 6;                // 0..7
  const int lane = tid & 63;
  const int l15 = lane & 15;
  const int quad = lane >> 4;
  const int col = w * 16 + l15;          // h column owned by this lane
  const int kb = quad * 8;

  __shared__ _Float16 hbuf[2][16][136];  // double-buffered h, +8 pad
  __shared__ _Float16 xt_lds[TS][16][8]; // x fp16, K-padded to 8 (d>=5 zero)

  for (int i = tid; i < 16 * 136; i += 512) ((_Float16*)hbuf[0])[i] = (_Float16)0.0f;
  for (int i = tid; i < TS * 16 * 8; i += 512) ((_Float16*)xt_lds)[i] = (_Float16)0.0f;
  __syncthreads();                       // zero-fill complete before data fill
  for (int i = tid; i < 16 * TS * INQ; i += 512) {
    int r = i / 640, rem = i - r * 640;
    int t = rem / 5, d = rem - t * 5;
    xt_lds[t][r][d] = (_Float16)x[(rloc + r) * 640 + rem];
  }

  // Persistent B fragments. B[k][n]: n = gate col, k = kt*32+quad*8+j
  half8 bh[4][4];                        // [kt][gate]
#pragma unroll
  for (int kt = 0; kt < 4; ++kt)
#pragma unroll
    for (int gt = 0; gt < 4; ++gt) {
      int gcol = gt * 128 + col;
      half8 v;
#pragma unroll
      for (int j = 0; j < 8; ++j) v[j] = whhT[(kt * 32 + kb + j) * NGATE + gcol];
      bh[kt][gt] = v;
    }
  half8 bx[4];                           // Wih1 as K=32-padded B frag (quad0, j<5 nonzero)
#pragma unroll
  for (int gt = 0; gt < 4; ++gt) {
    half8 v = {0, 0, 0, 0, 0, 0, 0, 0};
    if (quad == 0) {
#pragma unroll
      for (int j = 0; j < 5; ++j) v[j] = (_Float16)Wih1[(gt * 128 + col) * INQ + j];
    }
    bx[gt] = v;
  }
  f32x4 biasv[4];
#pragma unroll
  for (int gt = 0; gt < 4; ++gt) {
    float b = b1c[gt * 128 + col];
    biasv[gt][0] = b; biasv[gt][1] = b; biasv[gt][2] = b; biasv[gt][3] = b;
  }

  float c[4] = {0, 0, 0, 0};
  float ssum = 0.0f, ssq = 0.0f;
  _Float16* hs1w = hs1 + (size_t)wg * TS * 16 * HID;

  __syncthreads();                       // xt_lds staged

  for (int t = 0; t < TS; ++t) {
    // ---- pre-barrier: x-part (xt_lds is read-only; no h dependency) ----
    half8 ax = {0, 0, 0, 0, 0, 0, 0, 0};
    if (quad == 0) ax = *(const half8*)&xt_lds[t][l15][0];
    f32x4 acc[4];
#pragma unroll
    for (int gt = 0; gt < 4; ++gt)
      acc[gt] = __builtin_amdgcn_mfma_f32_16x16x32_f16(ax, bx[gt], biasv[gt], 0, 0, 0);
    BAR();                               // hbuf[t&1] writes from t-1 visible
    // ---- post-barrier: h-part ----
    half8 ah[4];
#pragma unroll
    for (int kt = 0; kt < 4; ++kt)
      ah[kt] = *(const half8*)&hbuf[t & 1][l15][kt * 32 + kb];
#pragma unroll
    for (int kt = 0; kt < 4; ++kt)
#pragma unroll
      for (int gt = 0; gt < 4; ++gt)
        acc[gt] = __builtin_amdgcn_mfma_f32_16x16x32_f16(ah[kt], bh[kt][gt], acc[gt], 0, 0, 0);
#pragma unroll
    for (int r = 0; r < 4; ++r) {
      _Float16 hh = lstm_cell(acc[0][r], acc[1][r], acc[2][r], acc[3][r], c[r]);
      float hr = (float)hh;
      ssum += hr; ssq += hr * hr;
      int row = quad * 4 + r;
      hbuf[(t + 1) & 1][row][col] = hh;
      hs1w[((size_t)t * 16 + row) * HID + col] = hh;   // fire-and-forget store
    }
  }
  float s = ssum, q = ssq;
  s += __shfl_xor(s, 16); s += __shfl_xor(s, 32);
  q += __shfl_xor(q, 16); q += __shfl_xor(q, 32);
  if (quad == 0) {
    atomicAdd(&s1sum[inp * HID + col], s);
    atomicAdd(&s1sq[inp * HID + col], q);
  }
}

// ---------------------------------------------------------------------------
__global__ void finalize1_kernel(const float* __restrict__ s1sum, const float* __restrict__ s1sq,
                                 const float* __restrict__ g1, const float* __restrict__ b1,
                                 float* __restrict__ scale1, float* __restrict__ shift1) {
  int i = blockIdx.x * 128 + threadIdx.x;   // 3 blocks x 128
  int h = i & 127;
  float m = s1sum[i] * INV_N;
  float v = s1sq[i] * INV_N - m * m;
  float s = g1[h] * rsqrtf(v + 1e-5f);
  scale1[i] = s;
  shift1[i] = b1[h] - m * s;
}

__global__ void w2s_kernel(const float* __restrict__ scale1, const float* __restrict__ Wih2,
                           _Float16* __restrict__ w2s) {
  int i = blockIdx.x * 256 + threadIdx.x;   // 768 blocks -> [3][128 k][512 g]
  int inp = i >> 16, rem = i & 65535, k = rem >> 9, g = rem & 511;
  w2s[i] = (_Float16)(scale1[inp * HID + k] * Wih2[g * HID + k]);
}

__global__ void bias2_kernel(const float* __restrict__ shift1, const float* __restrict__ Wih2,
                             const float* __restrict__ b2c, float* __restrict__ bias2eff) {
  int i = blockIdx.x * 512 + threadIdx.x;   // 3 blocks x 512
  int inp = i >> 9, g = i & 511;
  float acc = b2c[g];
  for (int h = 0; h < HID; ++h) acc += shift1[inp * HID + h] * Wih2[g * HID + h];
  bias2eff[i] = acc;
}

// ---------------------------------------------------------------------------
// LSTM layer 2: fused (folded-BN1) input GEMM + recurrence.
// 2-step-ahead prefetch of hs1 tiles; loads persist across BAR().
// ---------------------------------------------------------------------------
__global__ __launch_bounds__(512, 2) void lstm2_kernel(
    const _Float16* __restrict__ hs1,    // [96][128][16][128]
    const _Float16* __restrict__ whhT2,  // [128 k][512 g]
    const _Float16* __restrict__ w2s,    // [3][128 k][512 g]
    const float* __restrict__ bias2eff,  // [3][512]
    _Float16* __restrict__ h_last,       // [1536][128]
    float* __restrict__ s2sum, float* __restrict__ s2sq) {
  const int wg = blockIdx.x;
  const int inp = wg >> 5;
  const int gr0 = wg * 16;

  const int tid = threadIdx.x;
  const int w = tid >> 6;
  const int lane = tid & 63;
  const int l15 = lane & 15;
  const int quad = lane >> 4;
  const int col = w * 16 + l15;
  const int kb = quad * 8;

  __shared__ _Float16 hbuf[2][16][136];
  for (int i = tid; i < 16 * 136; i += 512) ((_Float16*)hbuf[0])[i] = (_Float16)0.0f;

  const _Float16* w2sI = w2s + (size_t)inp * HID * NGATE;
  half8 bh[4][4], bxw[4][4];
#pragma unroll
  for (int kt = 0; kt < 4; ++kt)
#pragma unroll
    for (int gt = 0; gt < 4; ++gt) {
      int gcol = gt * 128 + col;
      half8 vh, vx;
#pragma unroll
      for (int j = 0; j < 8; ++j) {
        vh[j] = whhT2[(kt * 32 + kb + j) * NGATE + gcol];
        vx[j] = w2sI[(kt * 32 + kb + j) * NGATE + gcol];
      }
      bh[kt][gt] = vh;
      bxw[kt][gt] = vx;
    }
  f32x4 biasv[4];
#pragma unroll
  for (int gt = 0; gt < 4; ++gt) {
    float b = bias2eff[inp * NGATE + gt * 128 + col];
    biasv[gt][0] = b; biasv[gt][1] = b; biasv[gt][2] = b; biasv[gt][3] = b;
  }

  const _Float16* hg = hs1 + (size_t)wg * TS * 16 * HID;
  half8 a2A[4], a2B[4];
#pragma unroll
  for (int kt = 0; kt < 4; ++kt) {
    a2A[kt] = *(const half8*)&hg[(size_t)l15 * HID + kt * 32 + kb];
    a2B[kt] = *(const half8*)&hg[((size_t)1 * 16 + l15) * HID + kt * 32 + kb];
  }

  float c[4] = {0, 0, 0, 0};
  float ssum = 0.0f, ssq = 0.0f;

  __syncthreads();                       // hbuf zero-init visible

  auto step = [&](int t, half8 (&cur)[4]) {
    // ---- pre-barrier: x-part from prefetched regs (loaded at t-2) ----
    f32x4 acc[4];
#pragma unroll
    for (int gt = 0; gt < 4; ++gt)
      acc[gt] = __builtin_amdgcn_mfma_f32_16x16x32_f16(cur[0], bxw[0][gt], biasv[gt], 0, 0, 0);
#pragma unroll
    for (int kt = 1; kt < 4; ++kt)
#pragma unroll
      for (int gt = 0; gt < 4; ++gt)
        acc[gt] = __builtin_amdgcn_mfma_f32_16x16x32_f16(cur[kt], bxw[kt][gt], acc[gt], 0, 0, 0);
    if (t + 2 < TS) {                    // prefetch t+2 into the regs just consumed
#pragma unroll
      for (int kt = 0; kt < 4; ++kt)
        cur[kt] = *(const half8*)&hg[((size_t)(t + 2) * 16 + l15) * HID + kt * 32 + kb];
    }
    BAR();                               // h(t-1) LDS writes visible; vmcnt untouched
    half8 ah[4];
#pragma unroll
    for (int kt = 0; kt < 4; ++kt)
      ah[kt] = *(const half8*)&hbuf[t & 1][l15][kt * 32 + kb];
#pragma unroll
    for (int kt = 0; kt < 4; ++kt)
#pragma unroll
      for (int gt = 0; gt < 4; ++gt)
        acc[gt] = __builtin_amdgcn_mfma_f32_16x16x32_f16(ah[kt], bh[kt][gt], acc[gt], 0, 0, 0);
#pragma unroll
    for (int r = 0; r < 4; ++r) {
      _Float16 hh = lstm_cell(acc[0][r], acc[1][r], acc[2][r], acc[3][r], c[r]);
      float hr = (float)hh;
      ssum += hr; ssq += hr * hr;
      int row = quad * 4 + r;
      hbuf[(t + 1) & 1][row][col] = hh;
      if (t == TS - 1) h_last[(gr0 + row) * HID + col] = hh;
    }
  };

  for (int t = 0; t < TS; t += 2) {
    step(t, a2A);
    step(t + 1, a2B);
  }

  float s = ssum, q = ssq;
  s += __shfl_xor(s, 16); s += __shfl_xor(s, 32);
  q += __shfl_xor(q, 16); q += __shfl_xor(q, 32);
  if (quad == 0) {
    atomicAdd(&s2sum[inp * HID + col], s);
    atomicAdd(&s2sq[inp * HID + col], q);
  }
}

// ---------------------------------------------------------------------------
// Head: BN2 finalize + FC + L2 normalize. 96 WGs x 16 rows.
// ---------------------------------------------------------------------------
__global__ __launch_bounds__(256, 1) void head_kernel(
    const _Float16* __restrict__ h_last,
    const float* __restrict__ s2sum, const float* __restrict__ s2sq,
    const float* __restrict__ g2, const float* __restrict__ b2,
    const float* __restrict__ fcW, const float* __restrict__ fcb,
    float* __restrict__ out) {
  const int wg = blockIdx.x;
  const int inp = wg >> 5;
  const int gr0 = wg * 16;
  const int tid = threadIdx.x;

  __shared__ float fcwT[128][132];       // fcwT[h][j] = fcW[j][h]
  __shared__ float bnh[16][132];
  __shared__ float s2[128], sh2[128];
  __shared__ float part[16][16];
  __shared__ float inv[16];

  if (tid < 128) {
    float m = s2sum[inp * HID + tid] * INV_N;
    float v = s2sq[inp * HID + tid] * INV_N - m * m;
    float s = g2[tid] * rsqrtf(v + 1e-5f);
    s2[tid] = s; sh2[tid] = b2[tid] - m * s;
  }
  for (int i = tid; i < 16384; i += 256) {
    int j = i >> 7, h = i & 127;
    fcwT[h][j] = fcW[i];
  }
  __syncthreads();
  {
    int row = tid >> 4, c0 = (tid & 15) * 8;
#pragma unroll
    for (int k = 0; k < 8; ++k) {
      int h = c0 + k;
      bnh[row][h] = (float)h_last[(gr0 + row) * HID + h] * s2[h] + sh2[h];
    }
  }
  __syncthreads();
  const int row = tid >> 4, jl = tid & 15;
  float emb[8];
  float sq = 0.0f;
#pragma unroll
  for (int jj = 0; jj < 8; ++jj) {
    int j = jl + jj * 16;
    float acc = fcb[j];
    for (int h = 0; h < HID; ++h) acc += bnh[row][h] * fcwT[h][j];
    emb[jj] = acc; sq += acc * acc;
  }
  part[row][jl] = sq;
  __syncthreads();
  if (tid < 16) {
    float s = 0.0f;
    for (int k = 0; k < 16; ++k) s += part[tid][k];
    float nrm = sqrtf(s);
    inv[tid] = 1.0f / fmaxf(nrm, 1e-12f);
  }
  __syncthreads();
#pragma unroll
  for (int jj = 0; jj < 8; ++jj)
    out[(gr0 + row) * HID + jl + jj * 16] = emb[jj] * inv[row];
}

// ---------------------------------------------------------------------------
extern "C" void kernel_launch(void* const* d_in, const int* in_sizes, int n_in,
                              void* d_out, int out_size, void* d_ws, size_t ws_size,
                              hipStream_t stream) {
  const float* a    = (const float*)d_in[0];
  const float* p    = (const float*)d_in[1];
  const float* nn   = (const float*)d_in[2];
  const float* Wih1 = (const float*)d_in[3];
  const float* Whh1 = (const float*)d_in[4];
  const float* bih1 = (const float*)d_in[5];
  const float* bhh1 = (const float*)d_in[6];
  const float* g1   = (const float*)d_in[7];
  const float* b1   = (const float*)d_in[8];
  const float* Wih2 = (const float*)d_in[9];
  const float* Whh2 = (const float*)d_in[10];
  const float* bih2 = (const float*)d_in[11];
  const float* bhh2 = (const float*)d_in[12];
  const float* g2   = (const float*)d_in[13];
  const float* b2   = (const float*)d_in[14];
  const float* fcW  = (const float*)d_in[15];
  const float* fcb  = (const float*)d_in[16];

  char* ws = (char*)d_ws;
  float* s1sum = (float*)(ws + 0);           // 384
  float* s1sq  = s1sum + 384;
  float* s2sum = s1sum + 768;
  float* s2sq  = s1sum + 1152;               // stats end @6144B
  float* b1c   = (float*)(ws + 6144);        // 512
  float* b2c   = b1c + 512;                  // ends @10240B
  float* scale1 = (float*)(ws + 10240);      // 384
  float* shift1 = scale1 + 384;              // ends @13312B
  float* bias2eff = (float*)(ws + 13312);    // 1536 -> ends @19456B
  _Float16* whhT1 = (_Float16*)(ws + 19456);   // 65536 -> @150528
  _Float16* whhT2 = (_Float16*)(ws + 150528);  // 65536 -> @281600
  _Float16* w2s   = (_Float16*)(ws + 281600);  // 196608 -> @674816
  _Float16* hlast = (_Float16*)(ws + 674816);  // 196608 -> @1068032
  _Float16* hs1   = (_Float16*)(ws + 1068032); // 25165824 -> ~51.4MB total

  hipMemsetAsync(ws, 0, 6144, stream);  // zero BN stats accumulators

  prep_whhT<<<512, 256, 0, stream>>>(Whh1, Whh2, whhT1, whhT2);
  prep_bias<<<4, 256, 0, stream>>>(bih1, bhh1, bih2, bhh2, b1c, b2c);
  lstm1_kernel<<<96, 512, 0, stream>>>(a, p, nn, Wih1, b1c, whhT1, hs1, s1sum, s1sq);
  finalize1_kernel<<<3, 128, 0, stream>>>(s1sum, s1sq, g1, b1, scale1, shift1);
  w2s_kernel<<<768, 256, 0, stream>>>(scale1, Wih2, w2s);
  bias2_kernel<<<3, 512, 0, stream>>>(shift1, Wih2, b2c, bias2eff);
  lstm2_kernel<<<96, 512, 0, stream>>>(hs1, whhT2, w2s, bias2eff, hlast, s2sum, s2sq);
  head_kernel<<<96, 256, 0, stream>>>(hlast, s2sum, s2sq, g2, b2, fcW, fcb, (float*)d_out);
}